// Round 5
// baseline (2622.110 us; speedup 1.0000x reference)
//
#include <hip/hip_runtime.h>
#include <hip/hip_bf16.h>

#define NBLK 128
#define NTHR 512
#define MTILE 64
#define KPAD 552                 // abuf row stride (elements); 1104 B, 16B-aligned
#define CHELEM (17*8*512)        // packed elements per 16-col chunk = 69632
#define LSTRIDE (16*CHELEM)      // packed elements per LSTM = 1,114,112

typedef __attribute__((ext_vector_type(8))) short short8;
typedef __attribute__((ext_vector_type(4))) float floatx4;

__device__ inline unsigned short f2bf(float x){
    unsigned u = __float_as_uint(x);
    return (unsigned short)((u + 0x7fffu + ((u>>16)&1u)) >> 16);
}
__device__ inline float bf2f(unsigned short v){ return __uint_as_float(((unsigned)v)<<16); }
__device__ inline float ex2(float x){ return __builtin_amdgcn_exp2f(x); }
__device__ inline float rcpn(float d){            // rcp + 1 Newton step
    float r = __builtin_amdgcn_rcpf(d);
    return r * (2.f - d*r);
}
#define LOG2E 1.4426950408889634f
__device__ inline float sigf(float x){ return rcpn(1.f + ex2(-LOG2E*x)); }
__device__ inline float tanh_(float x){ return 2.f*rcpn(1.f + ex2(-2.f*LOG2E*x)) - 1.f; }

// Packed layout: BP[chunk(16)][kt(17)][nt(8)][lane(64)][8]
// element = B[k][n], n = (chunk*8+nt)*16 + (lane&15), k = kt*32 + (lane>>4)*8 + j
// packed n decode: ch=n>>7, gate=(n>>5)&3, u=n&31 -> orig row = gate*512 + ch*32 + u
// K rows: 0..511 = W_hh, 512..515 = W_ih, 516 = b_ih+b_hh, 517..543 = 0
__global__ void prepack(const float* __restrict__ Wih, const float* __restrict__ Whh,
                        const float* __restrict__ bih, const float* __restrict__ bhh,
                        unsigned short* __restrict__ dst)
{
    int f = blockIdx.x*256 + threadIdx.x;
    if (f >= LSTRIDE) return;
    int j    = f & 7;
    int lane = (f>>3) & 63;
    int nt   = (f>>9) & 7;
    int rem  = f >> 12;
    int kt   = rem % 17;
    int chunk= rem / 17;
    int n = (chunk*8 + nt)*16 + (lane&15);
    int k = kt*32 + ((lane>>4)<<3) + j;
    int ch = n>>7, g = (n>>5)&3, u = n&31;
    int row = g*512 + ch*32 + u;
    float v = 0.f;
    if (k < 512)       v = Whh[row*512 + k];
    else if (k < 516)  v = Wih[row*4 + (k-512)];
    else if (k == 516) v = bih[row] + bhh[row];
    dst[f] = f2bf(v);
}

__global__ __launch_bounds__(NTHR, 2)
void lstm_all(const float* __restrict__ speed, const float* __restrict__ pos,
              const unsigned short* __restrict__ wpack,
              unsigned short* __restrict__ csaveG,
              unsigned short* __restrict__ hsaveG,
              const float* __restrict__ wfc, const float* __restrict__ bfc,
              const float* __restrict__ wemb, const float* __restrict__ bemb,
              float* __restrict__ out)
{
    // Double-buffered: pass reads abuf[rb], writes h to abuf[wbuf] -> no RAW race,
    // one barrier per step (Round-3-verified protocol at M=32, scaled to 64).
    __shared__ __align__(16) unsigned short abuf[2][MTILE][KPAD];  // 141312 B
    __shared__ float smallw[1040];                                 // 4160 B
    __shared__ float partial2[8][64][2];                           // 4096 B

    const int tid  = threadIdx.x;
    const int lane = tid & 63;
    const int wv   = tid >> 6;
    const int row0 = blockIdx.x * MTILE;
    const int l15  = lane & 15;
    const int lq   = lane >> 4;
    const short8 z8 = (short8){0,0,0,0,0,0,0,0};

    // ---- init: zero both buffers, smallw; bias-one in both; x_speed[0] in buf0 ----
    {
        for (int i = tid; i < 2*MTILE*(KPAD/8); i += NTHR) {
            int b = i / (MTILE*(KPAD/8));
            int rmd = i % (MTILE*(KPAD/8));
            int m = rmd / (KPAD/8), c8 = (rmd % (KPAD/8))*8;
            *(short8*)&abuf[b][m][c8] = z8;
        }
        for (int i = tid; i < 1024; i += NTHR) smallw[i] = wfc[i];
        if (tid < 2) smallw[1024+tid] = bfc[tid];
        if (tid < 8) smallw[1026+tid] = wemb[tid];
        if (tid < 4) smallw[1034+tid] = bemb[tid];
    }
    __syncthreads();
    if (tid < 128) abuf[tid>>6][tid&63][516] = 0x3F80;   // bias-one bf16(1.0), both buffers
    if (tid < 256) {
        int m = tid>>2, f3 = tid&3;
        abuf[0][m][512+f3] = f2bf(speed[((size_t)(row0+m)*16 + 0)*4 + f3]);
    }
    __syncthreads();

    float cc0[32], cc1[32];
    #pragma unroll
    for (int i = 0; i < 32; ++i) { cc0[i] = 0.f; cc1[i] = 0.f; }

    // One chunk-pass (128 gate-cols) of one LSTM step for M=64 rows, split into
    // two nt-halves (i,f then g,o) to keep acc at 64 VGPRs. s is a literal at
    // every call site; cc is a named array -> private indexing constant-folds.
    auto pass = [&](int rb, int wbuf, const unsigned short* wl, int s, float (&cc)[32]) {
        const int chunk = 2*wv + s;
        const unsigned short* bp0 = wl + (size_t)chunk*CHELEM + lane*8;
        float sI[32];
        #pragma unroll
        for (int half = 0; half < 2; ++half) {
            floatx4 acc[4][4];
            #pragma unroll
            for (int mf = 0; mf < 4; ++mf)
                #pragma unroll
                for (int i = 0; i < 4; ++i) acc[mf][i] = (floatx4){0.f,0.f,0.f,0.f};
            const unsigned short* bp2 = bp0 + half*4*512;
            short8 bA[4], bB[4];
            #pragma unroll
            for (int i = 0; i < 4; ++i) bA[i] = *(const short8*)(bp2 + i*512);
            #pragma unroll 1
            for (int kt = 0; kt < 16; kt += 2) {
                const unsigned short* p1 = bp2 + (kt+1)*4096;
                #pragma unroll
                for (int i = 0; i < 4; ++i) bB[i] = *(const short8*)(p1 + i*512);
                short8 a0 = *(const short8*)&abuf[rb][l15     ][kt*32 + lq*8];
                short8 a1 = *(const short8*)&abuf[rb][16 + l15][kt*32 + lq*8];
                short8 a2 = *(const short8*)&abuf[rb][32 + l15][kt*32 + lq*8];
                short8 a3 = *(const short8*)&abuf[rb][48 + l15][kt*32 + lq*8];
                #pragma unroll
                for (int i = 0; i < 4; ++i) {
                    acc[0][i] = __builtin_amdgcn_mfma_f32_16x16x32_bf16(a0, bA[i], acc[0][i], 0,0,0);
                    acc[1][i] = __builtin_amdgcn_mfma_f32_16x16x32_bf16(a1, bA[i], acc[1][i], 0,0,0);
                    acc[2][i] = __builtin_amdgcn_mfma_f32_16x16x32_bf16(a2, bA[i], acc[2][i], 0,0,0);
                    acc[3][i] = __builtin_amdgcn_mfma_f32_16x16x32_bf16(a3, bA[i], acc[3][i], 0,0,0);
                }
                const unsigned short* p2 = bp2 + (kt+2)*4096;
                #pragma unroll
                for (int i = 0; i < 4; ++i) bA[i] = *(const short8*)(p2 + i*512);
                a0 = *(const short8*)&abuf[rb][l15     ][(kt+1)*32 + lq*8];
                a1 = *(const short8*)&abuf[rb][16 + l15][(kt+1)*32 + lq*8];
                a2 = *(const short8*)&abuf[rb][32 + l15][(kt+1)*32 + lq*8];
                a3 = *(const short8*)&abuf[rb][48 + l15][(kt+1)*32 + lq*8];
                #pragma unroll
                for (int i = 0; i < 4; ++i) {
                    acc[0][i] = __builtin_amdgcn_mfma_f32_16x16x32_bf16(a0, bB[i], acc[0][i], 0,0,0);
                    acc[1][i] = __builtin_amdgcn_mfma_f32_16x16x32_bf16(a1, bB[i], acc[1][i], 0,0,0);
                    acc[2][i] = __builtin_amdgcn_mfma_f32_16x16x32_bf16(a2, bB[i], acc[2][i], 0,0,0);
                    acc[3][i] = __builtin_amdgcn_mfma_f32_16x16x32_bf16(a3, bB[i], acc[3][i], 0,0,0);
                }
            }
            {   // kt=16 tail: bA holds kt=16 (loaded during kt=14 iter). ALL accs use bA.
                short8 a0 = *(const short8*)&abuf[rb][l15     ][16*32 + lq*8];
                short8 a1 = *(const short8*)&abuf[rb][16 + l15][16*32 + lq*8];
                short8 a2 = *(const short8*)&abuf[rb][32 + l15][16*32 + lq*8];
                short8 a3 = *(const short8*)&abuf[rb][48 + l15][16*32 + lq*8];
                #pragma unroll
                for (int i = 0; i < 4; ++i) {
                    acc[0][i] = __builtin_amdgcn_mfma_f32_16x16x32_bf16(a0, bA[i], acc[0][i], 0,0,0);
                    acc[1][i] = __builtin_amdgcn_mfma_f32_16x16x32_bf16(a1, bA[i], acc[1][i], 0,0,0);
                    acc[2][i] = __builtin_amdgcn_mfma_f32_16x16x32_bf16(a2, bA[i], acc[2][i], 0,0,0);
                    acc[3][i] = __builtin_amdgcn_mfma_f32_16x16x32_bf16(a3, bA[i], acc[3][i], 0,0,0);
                }
            }
            if (half == 0) {
                // nt 0,1 = i-gate (up=0,1); nt 2,3 = f-gate. Fold f into c, hold sig(i).
                #pragma unroll
                for (int mf = 0; mf < 4; ++mf)
                    #pragma unroll
                    for (int up = 0; up < 2; ++up)
                        #pragma unroll
                        for (int r = 0; r < 4; ++r) {
                            int idx = (mf*2+up)*4 + r;
                            sI[idx] = sigf(acc[mf][0+up][r]);
                            cc[idx] = sigf(acc[mf][2+up][r]) * cc[idx];
                        }
            } else {
                // nt 4,5 = g-gate; nt 6,7 = o-gate. Finish cell update, write h -> wbuf.
                #pragma unroll
                for (int mf = 0; mf < 4; ++mf)
                    #pragma unroll
                    for (int up = 0; up < 2; ++up)
                        #pragma unroll
                        for (int r = 0; r < 4; ++r) {
                            int idx = (mf*2+up)*4 + r;
                            float cn = cc[idx] + sI[idx]*tanh_(acc[mf][0+up][r]);
                            cc[idx] = cn;
                            float h = sigf(acc[mf][2+up][r])*tanh_(cn);
                            abuf[wbuf][mf*16 + lq*4 + r][chunk*32 + up*16 + l15] = f2bf(h);
                        }
            }
        }
    };

    const unsigned short* wsp = wpack;
    const unsigned short* wpp = wpack + LSTRIDE;
    const unsigned short* wdp = wpack + 2*(size_t)LSTRIDE;
    unsigned short* hs_g = hsaveG + (size_t)blockIdx.x*MTILE*512;
    unsigned short* cs_g = csaveG + (size_t)blockIdx.x*MTILE*512;

    // ---- speed encoder ----
    #pragma unroll 1
    for (int t = 0; t < 16; ++t) {
        int rb = t&1, wbuf = (t+1)&1;
        pass(rb, wbuf, wsp, 0, cc0);
        pass(rb, wbuf, wsp, 1, cc1);
        if (t < 15 && tid < 256) {
            int m = tid>>2, f3 = tid&3;
            abuf[wbuf][m][512+f3] = f2bf(speed[((size_t)(row0+m)*16 + t+1)*4 + f3]);
        }
        __syncthreads();
    }
    // ---- speed -> pos transition ----
    // final h_s is in abuf[0]; stage h_s -> global (coalesced short8)
    for (int i = tid; i < MTILE*64; i += NTHR) {
        int m = i>>6, cb = (i&63)*8;
        *(short8*)&hs_g[m*512 + cb] = *(const short8*)&abuf[0][m][cb];
    }
    {   // scatter c (bf16, MFMA layout) -> abuf[1] cols 0..511 (it is idle now)
        #pragma unroll
        for (int s = 0; s < 2; ++s)
            #pragma unroll
            for (int mf = 0; mf < 4; ++mf)
                #pragma unroll
                for (int up = 0; up < 2; ++up)
                    #pragma unroll
                    for (int r = 0; r < 4; ++r) {
                        int idx = (mf*2+up)*4 + r;
                        int m = mf*16 + lq*4 + r;
                        int u = (2*wv+s)*32 + up*16 + l15;
                        abuf[1][m][u] = f2bf(s ? cc1[idx] : cc0[idx]);
                    }
    }
    __syncthreads();
    // abuf[1] c-staging -> global (coalesced); re-zero buf0 h; x_pos[0]; reset cc
    for (int i = tid; i < MTILE*64; i += NTHR) {
        int m = i>>6, cb = (i&63)*8;
        *(short8*)&cs_g[m*512 + cb] = *(const short8*)&abuf[1][m][cb];
        *(short8*)&abuf[0][m][cb] = z8;
    }
    if (tid < 256) {
        int m = tid>>2, f3 = tid&3;
        abuf[0][m][512+f3] = f2bf(pos[((size_t)(row0+m)*16 + 0)*4 + f3]);
    }
    #pragma unroll
    for (int i = 0; i < 32; ++i) { cc0[i] = 0.f; cc1[i] = 0.f; }
    __syncthreads();

    // ---- pos encoder ----
    #pragma unroll 1
    for (int t = 0; t < 16; ++t) {
        int rb = t&1, wbuf = (t+1)&1;
        pass(rb, wbuf, wpp, 0, cc0);
        pass(rb, wbuf, wpp, 1, cc1);
        if (t < 15 && tid < 256) {
            int m = tid>>2, f3 = tid&3;
            abuf[wbuf][m][512+f3] = f2bf(pos[((size_t)(row0+m)*16 + t+1)*4 + f3]);
        }
        __syncthreads();
    }
    // ---- combine: h0 = h_p + h_s (in buf0); c += c_s; x = pos[:,15,:] ----
    for (int i = tid; i < MTILE*64; i += NTHR) {
        int m = i>>6, cb = (i&63)*8;
        *(short8*)&abuf[1][m][cb] = *(const short8*)&cs_g[m*512 + cb];  // c_s -> buf1 staging
        short8 hv = *(const short8*)&abuf[0][m][cb];
        short8 sv = *(const short8*)&hs_g[m*512 + cb];
        short8 o;
        #pragma unroll
        for (int q = 0; q < 8; ++q)
            o[q] = (short)f2bf(bf2f((unsigned short)hv[q]) + bf2f((unsigned short)sv[q]));
        *(short8*)&abuf[0][m][cb] = o;
    }
    if (tid < 256) {
        int m = tid>>2, f3 = tid&3;
        abuf[0][m][512+f3] = f2bf(pos[((size_t)(row0+m)*16 + 15)*4 + f3]);
    }
    __syncthreads();
    {   // c += c_s (scattered LDS reads from buf1 staging)
        #pragma unroll
        for (int s = 0; s < 2; ++s)
            #pragma unroll
            for (int mf = 0; mf < 4; ++mf)
                #pragma unroll
                for (int up = 0; up < 2; ++up)
                    #pragma unroll
                    for (int r = 0; r < 4; ++r) {
                        int idx = (mf*2+up)*4 + r;
                        int m = mf*16 + lq*4 + r;
                        int u = (2*wv+s)*32 + up*16 + l15;
                        float v = bf2f(abuf[1][m][u]);
                        if (s) cc1[idx] += v; else cc0[idx] += v;
                    }
    }
    __syncthreads();   // all c-reads of buf1 done before decoder t=0 writes h into buf1

    // ---- decoder ----
    #pragma unroll 1
    for (int t = 0; t < 16; ++t) {
        int rb = t&1, wbuf = (t+1)&1;
        pass(rb, wbuf, wdp, 0, cc0);
        pass(rb, wbuf, wdp, 1, cc1);
        __syncthreads();
        {   // crossing partials: wave wv covers k-slice [wv*64, wv*64+64); lane = row
            int r = lane;
            float p0 = 0.f, p1 = 0.f;
            #pragma unroll
            for (int k = 0; k < 64; ++k) {
                float hv = bf2f(abuf[wbuf][r][wv*64 + k]);
                p0 += hv * smallw[       wv*64 + k];
                p1 += hv * smallw[512 +  wv*64 + k];
            }
            partial2[wv][r][0] = p0;
            partial2[wv][r][1] = p1;
        }
        __syncthreads();
        if (wv == 0) {
            int r = lane;
            float p0 = 0.f, p1 = 0.f;
            #pragma unroll
            for (int i = 0; i < 8; ++i) { p0 += partial2[i][r][0]; p1 += partial2[i][r][1]; }
            p0 += smallw[1024]; p1 += smallw[1025];
            float cr0 = fmaxf(p0, 0.f), cr1 = fmaxf(p1, 0.f);
            float mx = fmaxf(cr0, cr1);
            float e0 = ex2(LOG2E*(cr0-mx)), e1 = ex2(LOG2E*(cr1-mx));
            float inv = rcpn(e0+e1);
            out[((size_t)(row0+r))*32 + t*2 + 0] = e0*inv;
            out[((size_t)(row0+r))*32 + t*2 + 1] = e1*inv;
            #pragma unroll
            for (int e = 0; e < 4; ++e) {
                float lp = fmaxf(cr0*smallw[1026+e*2] + cr1*smallw[1026+e*2+1] + smallw[1034+e], 0.f);
                abuf[wbuf][r][512+e] = f2bf(lp);
            }
        }
        __syncthreads();
    }
}

extern "C" void kernel_launch(void* const* d_in, const int* in_sizes, int n_in,
                              void* d_out, int out_size, void* d_ws, size_t ws_size,
                              hipStream_t stream)
{
    (void)in_sizes; (void)n_in; (void)out_size; (void)ws_size;
    const float* speed = (const float*)d_in[0];
    const float* pos   = (const float*)d_in[1];
    const float* Ws_ih = (const float*)d_in[2];
    const float* Ws_hh = (const float*)d_in[3];
    const float* bs_ih = (const float*)d_in[4];
    const float* bs_hh = (const float*)d_in[5];
    const float* Wp_ih = (const float*)d_in[6];
    const float* Wp_hh = (const float*)d_in[7];
    const float* bp_ih = (const float*)d_in[8];
    const float* bp_hh = (const float*)d_in[9];
    const float* Wd_ih = (const float*)d_in[10];
    const float* Wd_hh = (const float*)d_in[11];
    const float* bd_ih = (const float*)d_in[12];
    const float* bd_hh = (const float*)d_in[13];
    const float* W_fc  = (const float*)d_in[14];
    const float* b_fc  = (const float*)d_in[15];
    const float* W_emb = (const float*)d_in[16];
    const float* b_emb = (const float*)d_in[17];

    unsigned short* wp = (unsigned short*)d_ws;
    unsigned short* csave = wp + 3*(size_t)LSTRIDE;                 // 8 MB
    unsigned short* hsave = csave + (size_t)NBLK*MTILE*512;         // 8 MB
    int gb = (LSTRIDE + 255) / 256;
    prepack<<<gb, 256, 0, stream>>>(Ws_ih, Ws_hh, bs_ih, bs_hh, wp);
    prepack<<<gb, 256, 0, stream>>>(Wp_ih, Wp_hh, bp_ih, bp_hh, wp + LSTRIDE);
    prepack<<<gb, 256, 0, stream>>>(Wd_ih, Wd_hh, bd_ih, bd_hh, wp + 2*(size_t)LSTRIDE);
    lstm_all<<<NBLK, NTHR, 0, stream>>>(speed, pos, wp, csave, hsave,
                                        W_fc, b_fc, W_emb, b_emb, (float*)d_out);
}